// Round 13
// baseline (163.859 us; speedup 1.0000x reference)
//
#include <hip/hip_runtime.h>
#include <hip/hip_bf16.h>
#include <math.h>

// ---------------------------------------------------------------------------
// Transformer block: bf16-MFMA GEMMs (2-phase prefetch, BK=64 epochs,
// 128x64 tile, split-K) + MFMA flash attention (static softmax, V^T LDS,
// permlane32_swap P exchange, l via ones-row of V^T in the PV MFMA,
// 8-wave blocks sharing staged K/V).
// B=2, S=1024, E=1024, G=64 heads of dim H=16, FF=4096.
// ---------------------------------------------------------------------------

#define E_DIM 1024
#define S_LEN 1024
#define B_SZ  2
#define G_HEADS 64
#define H_DIM 16
#define FF_DIM 4096
#define M_ROWS (B_SZ * S_LEN)   // 2048
#define QKV_N  (3 * E_DIM)      // 3072

// 0.25 * log2(e): folded into Q at the QKV GEMM epilogue; attention works in
// the log2 domain. Static softmax: log2-domain scores are bounded (sigma~0.5,
// max over 2M ~ 2.6; fp32 overflow needs s > 127) -> P = exp2(s), l = sum P.
#define QSCALE 0.36067376022224085f

// V^T LDS geometry: row stride 72 shorts (144 B -> every row 16B-aligned,
// bank pattern 4r%32 -> <=2-way, free); 17 rows (row 16 = ones for l).
#define VT_STRIDE 72
#define VT_BUF    1224          // 17 * 72 shorts per buffer

using bf16x8 = __attribute__((ext_vector_type(8))) short;
using f32x4  = __attribute__((ext_vector_type(4))) float;
using f32x16 = __attribute__((ext_vector_type(16))) float;
using ushort8 = __attribute__((ext_vector_type(8))) unsigned short;

static __device__ __forceinline__ unsigned short f2bf(float f) {
    union { float f; unsigned int u; } x; x.f = f;
    unsigned int r = x.u + 0x7fff + ((x.u >> 16) & 1);   // RNE
    return (unsigned short)(r >> 16);
}
// packed bf16 pair via v_cvt_pk_bf16_f32 (compiler-generated)
static __device__ __forceinline__ unsigned int pack2(float a, float b) {
    union { __hip_bfloat162 h; unsigned int u; } c;
    c.h = __float22bfloat162_rn(float2{a, b});   // a -> low 16, b -> high 16
    return c.u;
}

// ---------------------------------------------------------------------------
// cast fp32 -> bf16, 8 elements/thread
// ---------------------------------------------------------------------------
__global__ __launch_bounds__(256) void cast_kernel(
    const float* __restrict__ X, unsigned short* __restrict__ Xb)
{
    const size_t i = ((size_t)blockIdx.x * 256 + threadIdx.x) * 8;
    float4 a = *(const float4*)(X + i);
    float4 b = *(const float4*)(X + i + 4);
    ushort8 o;
    o[0] = f2bf(a.x); o[1] = f2bf(a.y); o[2] = f2bf(a.z); o[3] = f2bf(a.w);
    o[4] = f2bf(b.x); o[5] = f2bf(b.y); o[6] = f2bf(b.z); o[7] = f2bf(b.w);
    *(ushort8*)(Xb + i) = o;
}

// ---------------------------------------------------------------------------
// 4 square transposes (Wq,Wk,Wv -> Wt012 contiguous; Wo -> Wt3)
// ---------------------------------------------------------------------------
__global__ __launch_bounds__(256) void transpose_cast4_kernel(
    const float* __restrict__ W0, const float* __restrict__ W1_,
    const float* __restrict__ W2_, const float* __restrict__ W3_,
    unsigned short* __restrict__ Wt012, unsigned short* __restrict__ Wt3)
{
    __shared__ float tile[32][33];
    const int z = blockIdx.z;
    const float* W = (z == 0) ? W0 : (z == 1) ? W1_ : (z == 2) ? W2_ : W3_;
    unsigned short* Wo = (z < 3) ? (Wt012 + (size_t)z * E_DIM * E_DIM) : Wt3;
    const int n0 = blockIdx.x * 32, k0 = blockIdx.y * 32;
    const int t = threadIdx.x;
    const int r = t >> 3;
    const int c = (t & 7) * 4;

    float4 v = *(const float4*)(W + (size_t)(k0 + r) * E_DIM + n0 + c);
    tile[r][c] = v.x; tile[r][c + 1] = v.y; tile[r][c + 2] = v.z; tile[r][c + 3] = v.w;
    __syncthreads();

    ushort4 o;
    o.x = f2bf(tile[c + 0][r]); o.y = f2bf(tile[c + 1][r]);
    o.z = f2bf(tile[c + 2][r]); o.w = f2bf(tile[c + 3][r]);
    *(ushort4*)(Wo + (size_t)(n0 + r) * E_DIM + k0 + c) = o;
}

// ---------------------------------------------------------------------------
// FFN weight transposes, one launch: z=0 W1 [1024][4096] -> W1t [4096][1024],
// z=1 W2 [4096][1024] -> W2t [1024][4096]. Grid (128, 32, 2).
// ---------------------------------------------------------------------------
__global__ __launch_bounds__(256) void transpose_cast_ff_kernel(
    const float* __restrict__ W1_, const float* __restrict__ W2_,
    unsigned short* __restrict__ W1t, unsigned short* __restrict__ W2t)
{
    __shared__ float tile[32][33];
    const int z = blockIdx.z;
    const float* W = z ? W2_ : W1_;
    unsigned short* Wt = z ? W2t : W1t;
    const int N = z ? E_DIM : FF_DIM;      // W row length
    const int K = z ? FF_DIM : E_DIM;      // Wt row length
    const int n0 = (z ? blockIdx.y : blockIdx.x) * 32;
    const int k0 = (z ? blockIdx.x : blockIdx.y) * 32;
    const int t = threadIdx.x;
    const int r = t >> 3;
    const int c = (t & 7) * 4;

    float4 v = *(const float4*)(W + (size_t)(k0 + r) * N + n0 + c);
    tile[r][c] = v.x; tile[r][c + 1] = v.y; tile[r][c + 2] = v.z; tile[r][c + 3] = v.w;
    __syncthreads();

    ushort4 o;
    o.x = f2bf(tile[c + 0][r]); o.y = f2bf(tile[c + 1][r]);
    o.z = f2bf(tile[c + 2][r]); o.w = f2bf(tile[c + 3][r]);
    *(ushort4*)(Wt + (size_t)(n0 + r) * K + k0 + c) = o;
}

// ---------------------------------------------------------------------------
// bf16 MFMA GEMM, 2-phase prefetch with BK=64 epochs (R9-verified, untouched).
// SCALEQ: multiply columns [0, E_DIM) by QSCALE (QKV GEMM: pre-scale Q).
// ---------------------------------------------------------------------------
template<int ACT, int OUTBF, int SCALEQ>
__global__ __launch_bounds__(256) void gemm_mfma(
    const unsigned short* __restrict__ A,   // [M][Krow] bf16
    const unsigned short* __restrict__ Bt,  // [N][Krow] bf16
    const float* __restrict__ bias,         // [N] or null
    float* __restrict__ C0, float* __restrict__ C1,
    unsigned short* __restrict__ Cb,
    int Krow, int Kchunk, int ldc)
{
    // per buffer: sub0 {As 128x32 | Bs 64x32} sub1 {...} = 12288 shorts
    __shared__ __align__(16) unsigned short lds[2][12288];

    const int tid  = threadIdx.x;
    const int wave = tid >> 6;
    const int lane = tid & 63;
    const int wr = wave >> 1;
    const int wc = wave & 1;
    const int row0 = blockIdx.y * 128;
    const int col0 = blockIdx.x * 64;
    const int kbase = blockIdx.z * Kchunk;

    const int lr = lane & 15;
    const int lk = (lane >> 4) * 8;

    const int srow = (lane >> 2);
    const int scol = (lane & 3) * 8;

    f32x4 acc[4][2] = {};

    auto STAGE1 = [&](unsigned short* dstA, unsigned short* dstB, int k0) {
        #pragma unroll
        for (int i = 0; i < 2; ++i) {
            const int ci = wave + i * 4;
            const unsigned short* src =
                A + (size_t)(row0 + ci * 16 + srow) * Krow + k0 + scol;
            __builtin_amdgcn_global_load_lds(
                (const __attribute__((address_space(1))) void*)src,
                (__attribute__((address_space(3))) void*)(dstA + ci * 512),
                16, 0, 0);
        }
        {
            const unsigned short* src =
                Bt + (size_t)(col0 + wave * 16 + srow) * Krow + k0 + scol;
            __builtin_amdgcn_global_load_lds(
                (const __attribute__((address_space(1))) void*)src,
                (__attribute__((address_space(3))) void*)(dstB + wave * 512),
                16, 0, 0);
        }
    };
    auto STAGE = [&](int buf, int k0) {
        STAGE1(&lds[buf][0],    &lds[buf][4096],  k0);
        STAGE1(&lds[buf][6144], &lds[buf][10240], k0 + 32);
    };
    auto COMPUTE = [&](int buf, int sub) {
        const unsigned short* As = &lds[buf][sub * 6144];
        const unsigned short* Bs = As + 4096;
        bf16x8 a[4], b[2];
        #pragma unroll
        for (int mi = 0; mi < 4; ++mi)
            a[mi] = *(const bf16x8*)(As + (wr * 64 + mi * 16 + lr) * 32 + lk);
        #pragma unroll
        for (int ni = 0; ni < 2; ++ni)
            b[ni] = *(const bf16x8*)(Bs + (wc * 32 + ni * 16 + lr) * 32 + lk);
        #pragma unroll
        for (int mi = 0; mi < 4; ++mi)
            #pragma unroll
            for (int ni = 0; ni < 2; ++ni)
                acc[mi][ni] = __builtin_amdgcn_mfma_f32_16x16x32_bf16(
                    a[mi], b[ni], acc[mi][ni], 0, 0, 0);
    };

    const int nt = Kchunk >> 6;          // 64-K epochs

    STAGE(0, kbase);
    asm volatile("s_waitcnt vmcnt(0)" ::: "memory");
    __builtin_amdgcn_s_barrier();

    int cur = 0;
    for (int t = 0; t < nt; ++t) {
        if (t + 1 < nt) STAGE(cur ^ 1, kbase + (t + 1) * 64);
        COMPUTE(cur, 0);
        COMPUTE(cur, 1);
        asm volatile("s_waitcnt vmcnt(0)" ::: "memory");  // next epoch landed
        __builtin_amdgcn_s_barrier();                     // all ds_reads done
        cur ^= 1;
    }

    // epilogue: C/D layout col=lane&15, row=(lane>>4)*4+j
    float* Cw = blockIdx.z ? C1 : C0;
    #pragma unroll
    for (int mi = 0; mi < 4; ++mi) {
        #pragma unroll
        for (int ni = 0; ni < 2; ++ni) {
            const int cc  = col0 + wc * 32 + ni * 16 + (lane & 15);
            const int rr0 = row0 + wr * 64 + mi * 16 + ((lane >> 4) << 2);
            const float bv = bias ? bias[cc] : 0.f;
            #pragma unroll
            for (int j = 0; j < 4; ++j) {
                float v = acc[mi][ni][j] + bv;
                if (ACT == 1) v = fmaxf(v, 0.f);
                if (SCALEQ && cc < E_DIM) v *= QSCALE;
                if (OUTBF) Cb[(size_t)(rr0 + j) * ldc + cc] = f2bf(v);
                else       Cw[(size_t)(rr0 + j) * ldc + cc] = v;
            }
        }
    }
}

// ---------------------------------------------------------------------------
// MFMA flash attention, static softmax, 8-WAVE blocks.
// Block = 8 consecutive 32-row q-chunks (8p+wv) of one (b,g) head; 4 blocks
// per head (p = 3-bi, heavy blocks first; all 512 blocks co-resident at
// 2/CU). Waves 0-3 stage K (global_load_lds) and V (reg-stage transposed into
// Vt[h][key], row 16 = ones -> PV MFMA accumulates l in output col 16);
// waves 4-7 compute only -> per-CU staging work halves vs 4-wave blocks.
// V-fragment = 2x ds_read_b128. P half-exchange via v_permlane32_swap_b32
// (operands must hold DISTINCT values - R8 lesson).
// ---------------------------------------------------------------------------
__global__ __launch_bounds__(512) void attn_kernel(
    const unsigned short* __restrict__ qkv, unsigned short* __restrict__ Yb)
{
    __shared__ __align__(16) unsigned short Ks[2][1024];    // [buf][64key x 16h]
    __shared__ __align__(16) unsigned short Vt[2][VT_BUF];  // [buf][17h x 72key]

    const int bi = blockIdx.x >> 7;          // 0..3
    const int p  = 3 - bi;                   // heavy chunk-groups first
    const int bg = blockIdx.x & 127;
    const int g  = bg & (G_HEADS - 1);
    const int b  = bg >> 6;
    const int tid  = threadIdx.x;
    const int lane = tid & 63;
    const int l31  = lane & 31;
    const int hi   = lane >> 5;
    const int wv   = tid >> 6;               // 0..7
    const int tokb = b * S_LEN;

    const int q0   = (8 * p + wv) * 32;      // this wave's 32 q-rows
    const int qrow = q0 + l31;
    const int nt64 = 4 * p + 4;              // 64-key tiles for block's max chunk

    // Q B-frag: col=q=lane&31, k(h)=(lane>>5)*8+j  (pre-scaled by QSCALE)
    const bf16x8 qf = *(const bf16x8*)(
        qkv + (size_t)(tokb + qrow) * QKV_N + g * H_DIM + hi * 8);

    f32x16 acc = {};
    const f32x16 fz = {};

    // staging roles (tid < 256 only): waves 0-1 = K halves (global_load_lds);
    // waves 2-3 = V halves (reg-stage + transpose ds_write). Waves 4-7 idle
    // during stage (compute-only).
    const bool stager = (tid < 256);
    const int kv  = (tid >> 7) & 1;          // 0 = K, 1 = V (for tid<256)
    const int h64 = (tid >> 6) & 1;          // which 32-key half
    const int skey  = h64 * 32 + (lane >> 1);
    const int shalf = lane & 1;
    const size_t sgo = (size_t)(g * H_DIM + (1 + kv) * E_DIM + shalf * 8);

    auto STAGE = [&](int buf, int t64, ushort8& vreg) {
        const unsigned short* src =
            qkv + (size_t)(tokb + t64 * 64 + skey) * QKV_N + sgo;
        if (kv == 0) {
            __builtin_amdgcn_global_load_lds(
                (const __attribute__((address_space(1))) void*)src,
                (__attribute__((address_space(3))) void*)(&Ks[buf][h64 * 512]),
                16, 0, 0);
        } else {
            vreg = *(const ushort8*)src;     // 8 h's of key skey
        }
    };
    auto WRITE_V = [&](int buf, const ushort8& vreg) {
        if (kv == 1) {
            #pragma unroll
            for (int j = 0; j < 8; ++j)
                Vt[buf][(shalf * 8 + j) * VT_STRIDE + skey] = vreg[j];
        }
    };

    // V read row: lane l31==16 reads the ones-row (l accumulator);
    // other cols clamp to 0-15 (dupes, never stored). Hoisted out of loop.
    const int vrow = (l31 == 16) ? 16 : (l31 & 15);

    auto PROCESS = [&](int cur, int sub, int t0) {
        // K A-frag: row=key=lane&31, k(h)=(lane>>5)*8+j
        const bf16x8 kf = *(const bf16x8*)(&Ks[cur][(sub * 32 + l31) * 16 + hi * 8]);
        __builtin_amdgcn_s_setprio(1);
        f32x16 s = __builtin_amdgcn_mfma_f32_32x32x16_bf16(kf, qf, fz, 0, 0, 0);
        __builtin_amdgcn_s_setprio(0);

        // static softmax: P = exp2(score); masked keys contribute 0
        float pq[16];
        if (t0 == q0) {                      // diagonal tile: causal mask
            #pragma unroll
            for (int r = 0; r < 16; ++r) {
                const int key = t0 + (r & 3) + 8 * (r >> 2) + 4 * hi;
                pq[r] = (key > qrow) ? 0.f : exp2f(s[r]);
            }
        } else {
            #pragma unroll
            for (int r = 0; r < 16; ++r) pq[r] = exp2f(s[r]);
        }

        // pack P pairs; permlane32_swap assembles both PV A-frag word pairs
        unsigned int cw[8];
        #pragma unroll
        for (int r2 = 0; r2 < 8; ++r2) cw[r2] = pack2(pq[2 * r2], pq[2 * r2 + 1]);

        union { uint4 u; bf16x8 v; } pf0, pf1;
        {
            unsigned int a = cw[0], c = cw[2];
            asm volatile("v_permlane32_swap_b32 %0, %1" : "+v"(a), "+v"(c));
            pf0.u.x = a; pf0.u.z = c;
        }
        {
            unsigned int a = cw[1], c = cw[3];
            asm volatile("v_permlane32_swap_b32 %0, %1" : "+v"(a), "+v"(c));
            pf0.u.y = a; pf0.u.w = c;
        }
        {
            unsigned int a = cw[4], c = cw[6];
            asm volatile("v_permlane32_swap_b32 %0, %1" : "+v"(a), "+v"(c));
            pf1.u.x = a; pf1.u.z = c;
        }
        {
            unsigned int a = cw[5], c = cw[7];
            asm volatile("v_permlane32_swap_b32 %0, %1" : "+v"(a), "+v"(c));
            pf1.u.y = a; pf1.u.w = c;
        }

        // V B-frags from V^T: 8 consecutive keys of column vrow = one b128
        const unsigned short* vbase =
            &Vt[cur][vrow * VT_STRIDE + sub * 32 + hi * 8];
        const bf16x8 vb0 = *(const bf16x8*)(vbase);
        const bf16x8 vb1 = *(const bf16x8*)(vbase + 16);

        __builtin_amdgcn_s_setprio(1);
        acc = __builtin_amdgcn_mfma_f32_32x32x16_bf16(pf0.v, vb0, acc, 0, 0, 0);
        acc = __builtin_amdgcn_mfma_f32_32x32x16_bf16(pf1.v, vb1, acc, 0, 0, 0);
        __builtin_amdgcn_s_setprio(0);
    };

    // prologue: tile 0 + ones-row fill, published by one __syncthreads
    ushort8 vreg = {};
    if (stager) {
        STAGE(0, 0, vreg);
        if (kv == 1) {   // fill ones-row (row 16) of both buffers
            const int vt = tid - 128;
            Vt[vt >> 6][16 * VT_STRIDE + (vt & 63)] = 0x3F80;
        }
        WRITE_V(0, vreg);
    }
    __syncthreads();

    int cur = 0;
    for (int t = 0; t < nt64; ++t) {
        ushort8 vnext = {};
        const bool more = (t + 1 < nt64);
        if (more && stager) STAGE(cur ^ 1, t + 1, vnext);
        #pragma unroll
        for (int sub = 0; sub < 2; ++sub) {
            const int t0 = t * 64 + sub * 32;
            if (t0 <= q0) PROCESS(cur, sub, t0);   // wave-uniform guard
        }
        if (more && stager) WRITE_V(cur ^ 1, vnext);
        asm volatile("s_waitcnt vmcnt(0) lgkmcnt(0)" ::: "memory");
        __builtin_amdgcn_s_barrier();
        cur ^= 1;
    }

    // epilogue: acc row q=(r&3)+8*(r>>2)+4*hi, col h=lane&31.
    // l(row) sits in acc[r] of lane hi*32+16; broadcast with ALL lanes
    // active (divergent-branch shfl was R10's NaN), then store.
    float linv[16];
    #pragma unroll
    for (int r = 0; r < 16; ++r) {
        const float lr_ = __shfl(acc[r], (hi << 5) + 16);
        linv[r] = __builtin_amdgcn_rcpf(lr_);
    }
    if (l31 < H_DIM) {
        #pragma unroll
        for (int r = 0; r < 16; ++r) {
            const int q = (r & 3) + 8 * (r >> 2) + 4 * hi;
            Yb[(size_t)(tokb + q0 + q) * E_DIM + g * H_DIM + l31] =
                f2bf(acc[r] * linv[r]);
        }
    }
}

// ---------------------------------------------------------------------------
// out = LayerNorm(P0 + P1 + bias + resid) * gamma + beta
// (fuses split-K reduction + bias add). Optional bf16 copy.
// ---------------------------------------------------------------------------
__global__ __launch_bounds__(256) void add_ln2_kernel(
    const float* __restrict__ P0, const float* __restrict__ P1,
    const float* __restrict__ bias, const float* __restrict__ resid,
    const float* __restrict__ g, const float* __restrict__ be,
    float* __restrict__ O, unsigned short* __restrict__ Ob)
{
    const int row = blockIdx.x;
    const size_t base = (size_t)row * E_DIM;
    const int tid = threadIdx.x;

    float v[4];
    float s = 0.f;
    #pragma unroll
    for (int i = 0; i < 4; ++i) {
        int c = tid + i * 256;
        v[i] = P0[base + c] + P1[base + c] + bias[c] + resid[base + c];
        s += v[i];
    }

    __shared__ float red[256];
    red[tid] = s; __syncthreads();
    for (int st = 128; st >= 1; st >>= 1) {
        if (tid < st) red[tid] += red[tid + st];
        __syncthreads();
    }
    const float mu = red[0] * (1.f / E_DIM);
    __syncthreads();

    float s2 = 0.f;
    #pragma unroll
    for (int i = 0; i < 4; ++i) { float d = v[i] - mu; s2 += d * d; }
    red[tid] = s2; __syncthreads();
    for (int st = 128; st >= 1; st >>= 1) {
        if (tid < st) red[tid] += red[tid + st];
        __syncthreads();
    }
    const float rs = rsqrtf(red[0] * (1.f / E_DIM) + 1e-5f);

    #pragma unroll
    for (int i = 0; i < 4; ++i) {
        int c = tid + i * 256;
        float o = (v[i] - mu) * rs * g[c] + be[c];
        O[base + c] = o;
        if (Ob) Ob[base + c] = f2bf(o);
    }
}

// ---------------------------------------------------------------------------
// Launch
// ---------------------------------------------------------------------------
extern "C" void kernel_launch(void* const* d_in, const int* in_sizes, int n_in,
                              void* d_out, int out_size, void* d_ws, size_t ws_size,
                              hipStream_t stream)
{
    const float* x  = (const float*)d_in[0];
    const float* Wq = (const float*)d_in[1];
    const float* Wk = (const float*)d_in[2];
    const float* Wv = (const float*)d_in[3];
    const float* Wo = (const float*)d_in[4];
    const float* bo = (const float*)d_in[5];
    const float* W1 = (const float*)d_in[6];
    const float* b1 = (const float*)d_in[7];
    const float* W2 = (const float*)d_in[8];
    const float* b2 = (const float*)d_in[9];
    const float* g1  = (const float*)d_in[10];
    const float* be1 = (const float*)d_in[11];
    const float* g2  = (const float*)d_in[12];
    const float* be2 = (const float*)d_in[13];

    // workspace (MiB offsets); peak 52 MiB
    char* W = (char*)d_ws;
    const size_t MB = 1024 * 1024;
    unsigned short* xb   = (unsigned short*)(W + 0 * MB);   // [0,4)
    unsigned short* Wqkt = (unsigned short*)(W + 4 * MB);   // [4,10)
    unsigned short* qkvb = (unsigned short*)(W + 10 * MB);  // [10,22)
    unsigned short* yb   = (unsigned short*)(W + 22 * MB);  // [22,26)
    unsigned short* Wot  = (unsigned short*)(W + 26 * MB);  // [26,28)
    float* P_o0          = (float*)(W + 4 * MB);            // [4,12)  Wqkt/qkvb dead
    float* P_o1          = (float*)(W + 12 * MB);           // [12,20)
    unsigned short* x1b  = (unsigned short*)(W + 20 * MB);  // [20,24) qkvb/yb dead
    float* x1            = (float*)(W + 28 * MB);           // [28,36)
    unsigned short* W1t  = (unsigned short*)(W + 36 * MB);  // [36,44)
    unsigned short* W2t  = (unsigned short*)(W + 44 * MB);  // [44,52)
    unsigned short* ff1b = (unsigned short*)(W + 0 * MB);   // [0,16)  xb/P_o dead
    float* P_f1          = (float*)(W + 16 * MB);           // [16,24) x1b dead
    float* out           = (float*)d_out;                   // P_f0 = d_out

    dim3 blk(256);

    // 1) x -> bf16
    cast_kernel<<<dim3((M_ROWS * E_DIM) / (256 * 8)), blk, 0, stream>>>(x, xb);
    // 2) all weight prep up front: Wq|Wk|Wv -> Wqkt, Wo -> Wot; W1/W2 -> ffT
    transpose_cast4_kernel<<<dim3(32, 32, 4), blk, 0, stream>>>(Wq, Wk, Wv, Wo, Wqkt, Wot);
    transpose_cast_ff_kernel<<<dim3(128, 32, 2), blk, 0, stream>>>(W1, W2, W1t, W2t);
    // 3) qkv = x @ [Wq Wk Wv] -> bf16 [2048][3072], Q cols pre-scaled
    gemm_mfma<0, 1, 1><<<dim3(QKV_N / 64, M_ROWS / 128, 1), blk, 0, stream>>>(
        xb, Wqkt, nullptr, nullptr, nullptr, qkvb, E_DIM, E_DIM, QKV_N);
    // 4) attention -> yb bf16 (4 blocks per head, 8 waves each, heavy first)
    attn_kernel<<<dim3(B_SZ * G_HEADS * 4), dim3(512), 0, stream>>>(qkvb, yb);
    // 5) P_o = y @ Wo (split-K x2, fp32 partials, no bias)
    gemm_mfma<0, 0, 0><<<dim3(E_DIM / 64, M_ROWS / 128, 2), blk, 0, stream>>>(
        yb, Wot, nullptr, P_o0, P_o1, nullptr, E_DIM, E_DIM / 2, E_DIM);
    // 6) x1 = LN(P_o0 + P_o1 + bo + x)
    add_ln2_kernel<<<dim3(M_ROWS), blk, 0, stream>>>(P_o0, P_o1, bo, x, g1, be1, x1, x1b);
    // 7) ff1 = relu(x1 @ W1 + b1) -> bf16
    gemm_mfma<1, 1, 0><<<dim3(FF_DIM / 64, M_ROWS / 128, 1), blk, 0, stream>>>(
        x1b, W1t, b1, nullptr, nullptr, ff1b, E_DIM, E_DIM, FF_DIM);
    // 8) P_f = ff1 @ W2 (split-K x2; partial0 -> d_out)
    gemm_mfma<0, 0, 0><<<dim3(E_DIM / 64, M_ROWS / 128, 2), blk, 0, stream>>>(
        ff1b, W2t, nullptr, out, P_f1, nullptr, FF_DIM, FF_DIM / 2, E_DIM);
    // 9) out = LN(out + P_f1 + b2 + x1)
    add_ln2_kernel<<<dim3(M_ROWS), blk, 0, stream>>>(out, P_f1, b2, x1, g2, be2, out, nullptr);
}